// Round 3
// baseline (41130.859 us; speedup 1.0000x reference)
//
#include <hip/hip_runtime.h>
#include <hip/hip_bf16.h>

typedef _Float16 f16;
typedef f16  f16x8 __attribute__((ext_vector_type(8)));
typedef float f32x4 __attribute__((ext_vector_type(4)));

__device__ __forceinline__ f16x8 ld8h(const f16* p) {
    return *reinterpret_cast<const f16x8*>(p);
}
__device__ __forceinline__ void fsplit(float x, f16* hi, f16* lo) {
    f16 h = (f16)x;
    *hi = h;
    *lo = (f16)((x - (float)h) * 4096.0f);
}
__device__ __forceinline__ void tri(f16x8 ah, f16x8 al, const f16* bhp, const f16* blp,
                                    f32x4& gh, f32x4& gc) {
    f16x8 bh = ld8h(bhp), bl = ld8h(blp);
    gh = __builtin_amdgcn_mfma_f32_16x16x32_f16(ah, bh, gh, 0, 0, 0);
    gc = __builtin_amdgcn_mfma_f32_16x16x32_f16(al, bh, gc, 0, 0, 0);
    gc = __builtin_amdgcn_mfma_f32_16x16x32_f16(ah, bl, gc, 0, 0, 0);
}

// ---------------- element counts ----------------
constexpr size_t NXE   = 128ull*256*128;
constexpr size_t NPM   = 1024ull*4096;
constexpr size_t NWIH0 = 3072ull*384;
constexpr size_t NWIH12= 3072ull*256;
constexpr size_t NWIH3 = 3456ull*256;
constexpr size_t NWHH  = 3072ull*1024;
constexpr size_t NWHH3 = 3456ull*1152;
constexpr size_t NCEN  = 128ull*4096;
constexpr size_t NCTX  = 128ull*1024;
constexpr size_t NHMX  = 128ull*1152;   // uniform per-module h stride (padded)

// ---------------- workspace offsets (bytes) ----------------
constexpr size_t OFF_XH    = 0;
constexpr size_t OFF_XL    = OFF_XH + NXE*2;
constexpr size_t OFF_PMH   = OFF_XL + NXE*2;
constexpr size_t OFF_PML   = OFF_PMH + NPM*2;
constexpr size_t OFF_WIHH0 = OFF_PML + NPM*2;
constexpr size_t OFF_WIHH1 = OFF_WIHH0 + NWIH0*2;
constexpr size_t OFF_WIHH2 = OFF_WIHH1 + NWIH12*2;
constexpr size_t OFF_WIHH3 = OFF_WIHH2 + NWIH12*2;
constexpr size_t OFF_WIHL0 = OFF_WIHH3 + NWIH3*2;
constexpr size_t OFF_WIHL1 = OFF_WIHL0 + NWIH0*2;
constexpr size_t OFF_WIHL2 = OFF_WIHL1 + NWIH12*2;
constexpr size_t OFF_WIHL3 = OFF_WIHL2 + NWIH12*2;
constexpr size_t OFF_WHHH0 = OFF_WIHL3 + NWIH3*2;
constexpr size_t OFF_WHHH1 = OFF_WHHH0 + NWHH*2;
constexpr size_t OFF_WHHH2 = OFF_WHHH1 + NWHH*2;
constexpr size_t OFF_WHHH3 = OFF_WHHH2 + NWHH*2;
constexpr size_t OFF_WHHL0 = OFF_WHHH3 + NWHH3*2;
constexpr size_t OFF_WHHL1 = OFF_WHHL0 + NWHH*2;
constexpr size_t OFF_WHHL2 = OFF_WHHL1 + NWHH*2;
constexpr size_t OFF_WHHL3 = OFF_WHHL2 + NWHH*2;
constexpr size_t OFF_CENH  = OFF_WHHL3 + NWHH3*2;   // [2 parities] x NCEN f16
constexpr size_t OFF_CENL  = OFF_CENH + 2*NCEN*2;
constexpr size_t OFF_CTXH  = OFF_CENL + 2*NCEN*2;
constexpr size_t OFF_CTXL  = OFF_CTXH + NCTX*2;
constexpr size_t OFF_HH    = OFF_CTXL + NCTX*2;     // [(p*4+i)] x NHMX f16
constexpr size_t OFF_HL    = OFF_HH + 8*NHMX*2;
constexpr size_t OFF_HF    = OFF_HL + 8*NHMX*2;     // [(p*4+i)] x NHMX f32
constexpr size_t WS_NEED   = OFF_HF + 8*NHMX*4;     // ~116 MB

__device__ __forceinline__ f16* hh_ptr(char* ws, int p, int i) {
    return (f16*)(ws + OFF_HH + ((size_t)(p*4+i))*NHMX*2);
}
__device__ __forceinline__ f16* hl_ptr(char* ws, int p, int i) {
    return (f16*)(ws + OFF_HL + ((size_t)(p*4+i))*NHMX*2);
}
__device__ __forceinline__ float* hf_ptr(char* ws, int p, int i) {
    return (float*)(ws + OFF_HF + ((size_t)(p*4+i))*NHMX*4);
}

// ---------------- prep kernels ----------------
__global__ void k_split_n(const float* __restrict__ s, f16* __restrict__ hi,
                          f16* __restrict__ lo, int n) {
    int g = blockIdx.x*256 + threadIdx.x;
    if (g < n) fsplit(s[g], &hi[g], &lo[g]);
}

__global__ void k_pmt_split(const float* __restrict__ p0, const float* __restrict__ p1,
                            const float* __restrict__ p2, const float* __restrict__ p3,
                            f16* __restrict__ pmh, f16* __restrict__ pml) {
    int g = blockIdx.x*256 + threadIdx.x;
    if (g >= (int)NPM) return;
    int ngl = g >> 12;
    int k   = g & 4095;
    int i   = ngl >> 8;
    int n   = ngl & 255;
    const float* p = (i==0?p0 : i==1?p1 : i==2?p2 : p3);
    fsplit(p[(size_t)k*256 + n], &pmh[g], &pml[g]);
}

__global__ void k_init_cen(const float* __restrict__ ci, char* ws) {
    int g = blockIdx.x*256 + threadIdx.x;   // 4*128*1024
    if (g >= 4*128*1024) return;
    int i = g >> 17;
    int rem = g & 131071;
    int b = rem >> 10, c = rem & 1023;
    size_t idx = (size_t)b*4096 + i*1024 + c;
    fsplit(ci[g], (f16*)(ws + OFF_CENH) + idx, (f16*)(ws + OFF_CENL) + idx);
}

__global__ void k_init_mod(const float* __restrict__ mi, char* ws) {
    int g = blockIdx.x*256 + threadIdx.x;   // 3*128*1024
    if (g >= 3*128*1024) return;
    int i = g >> 17; int rem = g & 131071;
    float v = mi[g];
    hf_ptr(ws,0,i)[rem] = v;
    fsplit(v, &hh_ptr(ws,0,i)[rem], &hl_ptr(ws,0,i)[rem]);
}

__global__ void k_init_last(const float* __restrict__ ml, char* ws) {
    int g = blockIdx.x*256 + threadIdx.x;   // 128*1152
    if (g >= 128*1152) return;
    float v = ml[g];
    hf_ptr(ws,0,3)[g] = v;
    fsplit(v, &hh_ptr(ws,0,3)[g], &hl_ptr(ws,0,3)[g]);
}

// ---------------- step kernel 1: ctx = center @ pm ----------------
// 128 blocks: 2 m-tiles(64) x 64 n-tiles(16); 4 waves K-split (1024 each),
// wave = 4 m-frags x 1 n-frag; deterministic LDS reduction.
__global__ __launch_bounds__(256) void k_ctx(char* ws, int par) {
    __shared__ float red[4][64][16];
    const f16* cenh = (const f16*)(ws + OFF_CENH) + (size_t)par*NCEN;
    const f16* cenl = (const f16*)(ws + OFF_CENL) + (size_t)par*NCEN;
    const f16* pmh  = (const f16*)(ws + OFF_PMH);
    const f16* pml  = (const f16*)(ws + OFF_PML);
    f16* ctxh = (f16*)(ws + OFF_CTXH);
    f16* ctxl = (f16*)(ws + OFF_CTXL);

    int tid = threadIdx.x, lane = tid & 63, wv = tid >> 6;
    int bm = blockIdx.x & 1, bn = blockIdx.x >> 1;
    int m0 = bm*64, n0 = bn*16;
    int k0 = wv*1024;
    int kb = (lane >> 4)*8;
    int fr = lane & 15;

    const f16* Bh = pmh + (size_t)(n0 + fr)*4096 + k0 + kb;
    const f16* Bl = pml + (size_t)(n0 + fr)*4096 + k0 + kb;
    const f16* Ah[4]; const f16* Al[4];
    #pragma unroll
    for (int mf = 0; mf < 4; ++mf) {
        Ah[mf] = cenh + (size_t)(m0 + mf*16 + fr)*4096 + k0 + kb;
        Al[mf] = cenl + (size_t)(m0 + mf*16 + fr)*4096 + k0 + kb;
    }
    f32x4 hh[4] = {}, cr[4] = {};
    #pragma unroll 2
    for (int k = 0; k < 1024; k += 32) {
        f16x8 bh = ld8h(Bh + k), bl = ld8h(Bl + k);
        #pragma unroll
        for (int mf = 0; mf < 4; ++mf) {
            f16x8 ah = ld8h(Ah[mf] + k), al = ld8h(Al[mf] + k);
            hh[mf] = __builtin_amdgcn_mfma_f32_16x16x32_f16(ah, bh, hh[mf], 0, 0, 0);
            cr[mf] = __builtin_amdgcn_mfma_f32_16x16x32_f16(al, bh, cr[mf], 0, 0, 0);
            cr[mf] = __builtin_amdgcn_mfma_f32_16x16x32_f16(ah, bl, cr[mf], 0, 0, 0);
        }
    }
    #pragma unroll
    for (int mf = 0; mf < 4; ++mf)
        #pragma unroll
        for (int rr = 0; rr < 4; ++rr)
            red[wv][mf*16 + (lane>>4)*4 + rr][fr] = hh[mf][rr] + cr[mf][rr]*(1.0f/4096.0f);
    __syncthreads();
    for (int o = tid; o < 1024; o += 256) {
        int r = o >> 4, c = o & 15;
        float s = red[0][r][c] + red[1][r][c] + red[2][r][c] + red[3][r][c];
        size_t idx = (size_t)(m0 + r)*1024 + n0 + c;
        fsplit(s, &ctxh[idx], &ctxl[idx]);
    }
}

// ---------------- step kernel 2: fused gate GEMMs + GRU ----------------
// 528 blocks: tile = bid>>1 (264 col-tiles of 16 across 4 modules), rh = bid&1
// (row half of 64). Block computes 6 gate slabs (r,z,n x ih,hh) for its
// 64 rows x 16 h-cols, then the GRU elementwise, writing h/cen/out (parity^1).
__global__ __launch_bounds__(256) void k_fused(char* ws,
    const float* __restrict__ bih0, const float* __restrict__ bih1,
    const float* __restrict__ bih2, const float* __restrict__ bih3,
    const float* __restrict__ bhh0, const float* __restrict__ bhh1,
    const float* __restrict__ bhh2, const float* __restrict__ bhh3,
    float* __restrict__ out, int t, int par)
{
    int tid = threadIdx.x, lane = tid & 63, wv = tid >> 6;
    int tile = blockIdx.x >> 1, rh = blockIdx.x & 1;
    int i, jt;
    if (tile < 64)       { i = 0; jt = tile; }
    else if (tile < 128) { i = 1; jt = tile - 64; }
    else if (tile < 192) { i = 2; jt = tile - 128; }
    else                 { i = 3; jt = tile - 192; }
    const int H  = (i == 3) ? 1152 : 1024;
    const int K1 = (i == 0) ? 384 : 256;
    const int j0 = jt*16;

    const f16* Wih_h = (const f16*)(ws + (i==0?OFF_WIHH0 : i==1?OFF_WIHH1 : i==2?OFF_WIHH2 : OFF_WIHH3));
    const f16* Wih_l = (const f16*)(ws + (i==0?OFF_WIHL0 : i==1?OFF_WIHL1 : i==2?OFF_WIHL2 : OFF_WIHL3));
    const f16* Whh_h = (const f16*)(ws + (i==0?OFF_WHHH0 : i==1?OFF_WHHH1 : i==2?OFF_WHHH2 : OFF_WHHH3));
    const f16* Whh_l = (const f16*)(ws + (i==0?OFF_WHHL0 : i==1?OFF_WHHL1 : i==2?OFF_WHHL2 : OFF_WHHL3));

    int kb = (lane >> 4)*8;
    int fr = lane & 15;
    int mrow = rh*64 + wv*16 + fr;   // A-operand row for this lane

    // B pointers (slab s = gate r/z/n); W row = gate col = s*H + j0 + fr
    const f16 *B1h[3], *B1l[3], *B2h[3], *B2l[3];
    #pragma unroll
    for (int s = 0; s < 3; ++s) {
        size_t r1 = (size_t)(s*H + j0 + fr)*K1 + kb;
        size_t r2 = (size_t)(s*H + j0 + fr)*H + kb;
        B1h[s] = Wih_h + r1;  B1l[s] = Wih_l + r1;
        B2h[s] = Whh_h + r2;  B2l[s] = Whh_l + r2;
    }

    f32x4 g1h[3] = {}, g1c[3] = {}, g2h[3] = {}, g2c[3] = {};

    // ---- input-gate GEMMs: A = (i==0 ? [x_t | ctx0] : ctx_i), K = K1 ----
    {
        const f16* ch = (const f16*)(ws + OFF_CTXH);
        const f16* cl = (const f16*)(ws + OFF_CTXL);
        int coff = (i == 0) ? 0 : i*256;
        const f16* Ach = ch + (size_t)mrow*1024 + coff + kb;
        const f16* Acl = cl + (size_t)mrow*1024 + coff + kb;
        if (i == 0) {
            const f16* Axh = (const f16*)(ws + OFF_XH) + ((size_t)mrow*256 + t)*128 + kb;
            const f16* Axl = (const f16*)(ws + OFF_XL) + ((size_t)mrow*256 + t)*128 + kb;
            #pragma unroll 2
            for (int k = 0; k < 128; k += 32) {
                f16x8 ah = ld8h(Axh + k), al = ld8h(Axl + k);
                #pragma unroll
                for (int s = 0; s < 3; ++s) tri(ah, al, B1h[s]+k, B1l[s]+k, g1h[s], g1c[s]);
            }
            #pragma unroll 2
            for (int k = 128; k < 384; k += 32) {
                f16x8 ah = ld8h(Ach + k - 128), al = ld8h(Acl + k - 128);
                #pragma unroll
                for (int s = 0; s < 3; ++s) tri(ah, al, B1h[s]+k, B1l[s]+k, g1h[s], g1c[s]);
            }
        } else {
            #pragma unroll 2
            for (int k = 0; k < 256; k += 32) {
                f16x8 ah = ld8h(Ach + k), al = ld8h(Acl + k);
                #pragma unroll
                for (int s = 0; s < 3; ++s) tri(ah, al, B1h[s]+k, B1l[s]+k, g1h[s], g1c[s]);
            }
        }
    }
    // ---- hidden-gate GEMMs: A = h_prev (parity par), K = H ----
    {
        const f16* Ahh = hh_ptr(ws, par, i) + (size_t)mrow*H + kb;
        const f16* Ahl = hl_ptr(ws, par, i) + (size_t)mrow*H + kb;
        #pragma unroll 2
        for (int k = 0; k < H; k += 32) {
            f16x8 ah = ld8h(Ahh + k), al = ld8h(Ahl + k);
            #pragma unroll
            for (int s = 0; s < 3; ++s) tri(ah, al, B2h[s]+k, B2l[s]+k, g2h[s], g2c[s]);
        }
    }

    // ---- GRU elementwise epilogue (registers only) ----
    const float* bihp = (i==0?bih0 : i==1?bih1 : i==2?bih2 : bih3);
    const float* bhhp = (i==0?bhh0 : i==1?bhh1 : i==2?bhh2 : bhh3);
    int j = j0 + fr;                      // h column this lane owns
    float bir = bihp[j], biz = bihp[H + j], bin = bihp[2*H + j];
    float bhr = bhhp[j], bhz = bhhp[H + j], bhn = bhhp[2*H + j];

    const float* hfP = hf_ptr(ws, par, i);
    float* hfN = hf_ptr(ws, par^1, i);
    f16*   hhN = hh_ptr(ws, par^1, i);
    f16*   hlN = hl_ptr(ws, par^1, i);
    f16* cenhN = (f16*)(ws + OFF_CENH) + (size_t)(par^1)*NCEN;
    f16* cenlN = (f16*)(ws + OFF_CENL) + (size_t)(par^1)*NCEN;

    const float inv = 1.0f/4096.0f;
    int mbase = rh*64 + wv*16 + (lane>>4)*4;
    #pragma unroll
    for (int rr = 0; rr < 4; ++rr) {
        float ir  = g1h[0][rr] + g1c[0][rr]*inv + bir;
        float iz  = g1h[1][rr] + g1c[1][rr]*inv + biz;
        float inn = g1h[2][rr] + g1c[2][rr]*inv + bin;
        float hr  = g2h[0][rr] + g2c[0][rr]*inv + bhr;
        float hz  = g2h[1][rr] + g2c[1][rr]*inv + bhz;
        float hn  = g2h[2][rr] + g2c[2][rr]*inv + bhn;
        float rg = 1.f/(1.f + expf(-(ir + hr)));
        float zg = 1.f/(1.f + expf(-(iz + hz)));
        float ng = tanhf(inn + rg*hn);
        int m = mbase + rr;
        float hp = hfP[(size_t)m*H + j];
        float hnew = (1.f - zg)*ng + zg*hp;
        hfN[(size_t)m*H + j] = hnew;
        fsplit(hnew, &hhN[(size_t)m*H + j], &hlN[(size_t)m*H + j]);
        if (i < 3) {
            size_t ci = (size_t)m*4096 + i*1024 + j;
            fsplit(hnew, &cenhN[ci], &cenlN[ci]);
        } else if (j >= 128) {
            size_t ci = (size_t)m*4096 + 3072 + (j - 128);
            fsplit(hnew, &cenhN[ci], &cenlN[ci]);
        } else {
            out[((size_t)m*256 + t)*128 + j] = hnew;
        }
    }
}

// ---------------- host ----------------
extern "C" void kernel_launch(void* const* d_in, const int* in_sizes, int n_in,
                              void* d_out, int out_size, void* d_ws, size_t ws_size,
                              hipStream_t stream)
{
    char* ws = (char*)d_ws;
    const float* inp   = (const float*)d_in[0];
    const float* cini  = (const float*)d_in[1];
    const float* mini  = (const float*)d_in[2];
    const float* mlast = (const float*)d_in[3];
    const float *pm[4], *wih[4], *whh[4], *bih[4], *bhh[4];
    for (int i = 0; i < 4; ++i) {
        pm[i]  = (const float*)d_in[4 + 5*i];
        wih[i] = (const float*)d_in[5 + 5*i];
        whh[i] = (const float*)d_in[6 + 5*i];
        bih[i] = (const float*)d_in[7 + 5*i];
        bhh[i] = (const float*)d_in[8 + 5*i];
    }
    float* out = (float*)d_out;

    k_split_n<<<16384, 256, 0, stream>>>(inp, (f16*)(ws+OFF_XH), (f16*)(ws+OFF_XL), (int)NXE);
    k_pmt_split<<<16384, 256, 0, stream>>>(pm[0], pm[1], pm[2], pm[3],
                                           (f16*)(ws+OFF_PMH), (f16*)(ws+OFF_PML));
    k_split_n<<<4608, 256, 0, stream>>>(wih[0], (f16*)(ws+OFF_WIHH0), (f16*)(ws+OFF_WIHL0), (int)NWIH0);
    k_split_n<<<3072, 256, 0, stream>>>(wih[1], (f16*)(ws+OFF_WIHH1), (f16*)(ws+OFF_WIHL1), (int)NWIH12);
    k_split_n<<<3072, 256, 0, stream>>>(wih[2], (f16*)(ws+OFF_WIHH2), (f16*)(ws+OFF_WIHL2), (int)NWIH12);
    k_split_n<<<3456, 256, 0, stream>>>(wih[3], (f16*)(ws+OFF_WIHH3), (f16*)(ws+OFF_WIHL3), (int)NWIH3);
    k_split_n<<<12288, 256, 0, stream>>>(whh[0], (f16*)(ws+OFF_WHHH0), (f16*)(ws+OFF_WHHL0), (int)NWHH);
    k_split_n<<<12288, 256, 0, stream>>>(whh[1], (f16*)(ws+OFF_WHHH1), (f16*)(ws+OFF_WHHL1), (int)NWHH);
    k_split_n<<<12288, 256, 0, stream>>>(whh[2], (f16*)(ws+OFF_WHHH2), (f16*)(ws+OFF_WHHL2), (int)NWHH);
    k_split_n<<<15552, 256, 0, stream>>>(whh[3], (f16*)(ws+OFF_WHHH3), (f16*)(ws+OFF_WHHL3), (int)NWHH3);
    k_init_cen<<<2048, 256, 0, stream>>>(cini, ws);
    k_init_mod<<<1536, 256, 0, stream>>>(mini, ws);
    k_init_last<<<576, 256, 0, stream>>>(mlast, ws);

    for (int t = 0; t < 256; ++t) {
        int par = t & 1;
        k_ctx<<<128, 256, 0, stream>>>(ws, par);
        k_fused<<<528, 256, 0, stream>>>(ws,
            bih[0], bih[1], bih[2], bih[3],
            bhh[0], bhh[1], bhh[2], bhh[3],
            out, t, par);
    }
    (void)in_sizes; (void)n_in; (void)out_size; (void)ws_size; (void)WS_NEED;
}

// Round 4
// 14594.514 us; speedup vs baseline: 2.8182x; 2.8182x over previous
//
#include <hip/hip_runtime.h>
#include <hip/hip_bf16.h>

typedef _Float16 f16;
typedef f16  f16x8 __attribute__((ext_vector_type(8)));
typedef float f32x4 __attribute__((ext_vector_type(4)));

__device__ __forceinline__ f16x8 ld8h(const f16* p){ return *reinterpret_cast<const f16x8*>(p); }
__device__ __forceinline__ void fsplit(float x, f16* hi, f16* lo){
    f16 h=(f16)x; *hi=h; *lo=(f16)((x-(float)h)*4096.0f);
}
// fragment-major offset: 16(n)x32(k) fragment = 512 contiguous f16; within-frag = lane*8+e
__device__ __forceinline__ size_t fragoff(int n, int k, int Kc){
    return ((size_t)(n>>4)*Kc + (k>>5))*512 + (size_t)((((k&31)>>3)*16 + (n&15))*8 + (k&7));
}

// ---------------- element counts ----------------
constexpr size_t NXE   = 128ull*256*128;
constexpr size_t NPM   = 1024ull*4096;
constexpr size_t NWIH0 = 3072ull*384;
constexpr size_t NWIH12= 3072ull*256;
constexpr size_t NWIH3 = 3456ull*256;
constexpr size_t NWHH  = 3072ull*1024;
constexpr size_t NWHH3 = 3456ull*1152;
constexpr size_t NCEN  = 128ull*4096;
constexpr size_t NCTX  = 128ull*1024;
constexpr size_t NHMX  = 128ull*1152;   // uniform per-(parity,module) h stride

// ---------------- workspace offsets (bytes) ----------------
constexpr size_t OFF_XH    = 0;
constexpr size_t OFF_XL    = OFF_XH + NXE*2;
constexpr size_t OFF_PMH   = OFF_XL + NXE*2;
constexpr size_t OFF_PML   = OFF_PMH + NPM*2;
constexpr size_t OFF_WIHH0 = OFF_PML + NPM*2;
constexpr size_t OFF_WIHH1 = OFF_WIHH0 + NWIH0*2;
constexpr size_t OFF_WIHH2 = OFF_WIHH1 + NWIH12*2;
constexpr size_t OFF_WIHH3 = OFF_WIHH2 + NWIH12*2;
constexpr size_t OFF_WIHL0 = OFF_WIHH3 + NWIH3*2;
constexpr size_t OFF_WIHL1 = OFF_WIHL0 + NWIH0*2;
constexpr size_t OFF_WIHL2 = OFF_WIHL1 + NWIH12*2;
constexpr size_t OFF_WIHL3 = OFF_WIHL2 + NWIH12*2;
constexpr size_t OFF_WHHH0 = OFF_WIHL3 + NWIH3*2;
constexpr size_t OFF_WHHH1 = OFF_WHHH0 + NWHH*2;
constexpr size_t OFF_WHHH2 = OFF_WHHH1 + NWHH*2;
constexpr size_t OFF_WHHH3 = OFF_WHHH2 + NWHH*2;
constexpr size_t OFF_WHHL0 = OFF_WHHH3 + NWHH3*2;
constexpr size_t OFF_WHHL1 = OFF_WHHL0 + NWHH*2;
constexpr size_t OFF_WHHL2 = OFF_WHHL1 + NWHH*2;
constexpr size_t OFF_WHHL3 = OFF_WHHL2 + NWHH*2;
constexpr size_t OFF_CENH  = OFF_WHHL3 + NWHH3*2;   // [2 parities]
constexpr size_t OFF_CENL  = OFF_CENH + 2*NCEN*2;
constexpr size_t OFF_CTXH  = OFF_CENL + 2*NCEN*2;
constexpr size_t OFF_CTXL  = OFF_CTXH + NCTX*2;
constexpr size_t OFF_HH    = OFF_CTXL + NCTX*2;     // [(p*4+i)]
constexpr size_t OFF_HL    = OFF_HH + 8*NHMX*2;
constexpr size_t OFF_HF    = OFF_HL + 8*NHMX*2;     // fp32
constexpr size_t WS_NEED   = OFF_HF + 8*NHMX*4;     // ~116 MB

__device__ __forceinline__ f16* hh_ptr(char* ws,int p,int i){ return (f16*)(ws+OFF_HH+((size_t)(p*4+i))*NHMX*2); }
__device__ __forceinline__ f16* hl_ptr(char* ws,int p,int i){ return (f16*)(ws+OFF_HL+((size_t)(p*4+i))*NHMX*2); }
__device__ __forceinline__ float* hf_ptr(char* ws,int p,int i){ return (float*)(ws+OFF_HF+((size_t)(p*4+i))*NHMX*4); }

// ---------------- prep: repack to fragment-major ----------------
// W row-major [N x K] -> frag-major hi/lo. grid = N blocks.
__global__ void k_repack_w(const float* __restrict__ src, f16* __restrict__ hi,
                           f16* __restrict__ lo, int K){
    int n = blockIdx.x;
    const float* row = src + (size_t)n*K;
    int Kc = K >> 5;
    for (int k8 = threadIdx.x*8; k8 < K; k8 += 2048) {
        f16x8 hv, lv;
        #pragma unroll
        for (int e = 0; e < 8; ++e) { f16 a,b; fsplit(row[k8+e], &a, &b); hv[e]=a; lv[e]=b; }
        size_t d = fragoff(n, k8, Kc);
        *reinterpret_cast<f16x8*>(hi + d) = hv;
        *reinterpret_cast<f16x8*>(lo + d) = lv;
    }
}

// pm_i [4096 x 256] (k-major) -> B frag-major over (n=1024, k=4096). grid = 512 blocks (8 k-rows each).
__global__ void k_repack_pm(const float* __restrict__ p0, const float* __restrict__ p1,
                            const float* __restrict__ p2, const float* __restrict__ p3,
                            f16* __restrict__ hi, f16* __restrict__ lo){
    int k0 = blockIdx.x * 8;
    for (int c = threadIdx.x; c < 1024; c += 256) {
        int i = c >> 8, nl = c & 255;
        const float* p = (i==0?p0 : i==1?p1 : i==2?p2 : p3);
        f16x8 hv, lv;
        #pragma unroll
        for (int e = 0; e < 8; ++e) { f16 a,b; fsplit(p[(size_t)(k0+e)*256 + nl], &a, &b); hv[e]=a; lv[e]=b; }
        // frag offset for (n=c, k=k0..k0+7): consecutive e NOT contiguous (k-dim), store scalar
        #pragma unroll
        for (int e = 0; e < 8; ++e) { size_t d = fragoff(c, k0+e, 128); hi[d]=hv[e]; lo[d]=lv[e]; }
    }
}

// x [128,256,128] -> per-t frag-major (Kc=4). grid = NXE/8/256 blocks.
__global__ void k_repack_x(const float* __restrict__ src, f16* __restrict__ hi, f16* __restrict__ lo){
    size_t g = ((size_t)blockIdx.x*256 + threadIdx.x) * 8;
    if (g >= NXE) return;
    int m = (int)(g >> 15), t = (int)((g >> 7) & 255), d0 = (int)(g & 127);
    f16x8 hv, lv;
    #pragma unroll
    for (int e = 0; e < 8; ++e) { f16 a,b; fsplit(src[g+e], &a, &b); hv[e]=a; lv[e]=b; }
    size_t d = (size_t)t*16384 + fragoff(m, d0, 4);
    *reinterpret_cast<f16x8*>(hi + d) = hv;
    *reinterpret_cast<f16x8*>(lo + d) = lv;
}

// center_init [4,128,1024] -> cen frag-major (Kc=128), parity 0
__global__ void k_init_cen(const float* __restrict__ ci, char* ws){
    size_t g = ((size_t)blockIdx.x*256 + threadIdx.x) * 8;
    if (g >= 4ull*128*1024) return;
    int i = (int)(g >> 17), b = (int)((g >> 10) & 127), c = (int)(g & 1023);
    f16* hi = (f16*)(ws + OFF_CENH);
    f16* lo = (f16*)(ws + OFF_CENL);
    f16x8 hv, lv;
    #pragma unroll
    for (int e = 0; e < 8; ++e) { f16 a,bb; fsplit(ci[g+e], &a, &bb); hv[e]=a; lv[e]=bb; }
    size_t d = fragoff(b, i*1024 + c, 128);
    *reinterpret_cast<f16x8*>(hi + d) = hv;
    *reinterpret_cast<f16x8*>(lo + d) = lv;
}

// mod_init [3,128,1024] -> h frag (Kc=32) + hf, parity 0
__global__ void k_init_mod(const float* __restrict__ mi, char* ws){
    size_t g = ((size_t)blockIdx.x*256 + threadIdx.x) * 8;
    if (g >= 3ull*128*1024) return;
    int i = (int)(g >> 17), b = (int)((g >> 10) & 127), j = (int)(g & 1023);
    float* hf = hf_ptr(ws, 0, i);
    f16 *hh = hh_ptr(ws, 0, i), *hl = hl_ptr(ws, 0, i);
    f16x8 hv, lv;
    #pragma unroll
    for (int e = 0; e < 8; ++e) {
        float v = mi[g+e]; hf[(size_t)b*1024 + j + e] = v;
        f16 a,bb; fsplit(v, &a, &bb); hv[e]=a; lv[e]=bb;
    }
    size_t d = fragoff(b, j, 32);
    *reinterpret_cast<f16x8*>(hh + d) = hv;
    *reinterpret_cast<f16x8*>(hl + d) = lv;
}

// mod_init_last [128,1152] -> h3 frag (Kc=36) + hf3, parity 0. grid = 128 blocks.
__global__ void k_init_last(const float* __restrict__ ml, char* ws){
    int b = blockIdx.x;
    float* hf = hf_ptr(ws, 0, 3);
    f16 *hh = hh_ptr(ws, 0, 3), *hl = hl_ptr(ws, 0, 3);
    for (int j = threadIdx.x*8; j < 1152; j += 2048) {
        f16x8 hv, lv;
        #pragma unroll
        for (int e = 0; e < 8; ++e) {
            float v = ml[(size_t)b*1152 + j + e]; hf[(size_t)b*1152 + j + e] = v;
            f16 a,bb; fsplit(v, &a, &bb); hv[e]=a; lv[e]=bb;
        }
        size_t d = fragoff(b, j, 36);
        *reinterpret_cast<f16x8*>(hh + d) = hv;
        *reinterpret_cast<f16x8*>(hl + d) = lv;
    }
}

// ---------------- step kernel 1: ctx = center @ pm ----------------
// 256 blocks x 512 thr: tile (32 rows x 16 cols), 8-wave K-split (512 each), LDS reduce.
__global__ __launch_bounds__(512) void k_ctx(char* ws, int par){
    __shared__ float red[8][32][17];
    const f16* cenh = (const f16*)(ws + OFF_CENH) + (size_t)par*NCEN;
    const f16* cenl = (const f16*)(ws + OFF_CENL) + (size_t)par*NCEN;
    const f16* pmh  = (const f16*)(ws + OFF_PMH);
    const f16* pml  = (const f16*)(ws + OFF_PML);
    int tid = threadIdx.x, lane = tid & 63, wv = tid >> 6;
    int bm = blockIdx.x >> 6, bn = blockIdx.x & 63;
    size_t lb = (size_t)lane*8;
    size_t a0 = ((size_t)(bm*2)*128 + wv*16)*512 + lb;
    size_t a1 = a0 + 128*512;
    size_t bb = ((size_t)bn*128 + wv*16)*512 + lb;
    f32x4 h0={},h1={},c0={},c1={};
    #pragma unroll 4
    for (int kc = 0; kc < 16; ++kc) {
        f16x8 bh = ld8h(pmh + bb + kc*512), bl = ld8h(pml + bb + kc*512);
        f16x8 ah0 = ld8h(cenh + a0 + kc*512), al0 = ld8h(cenl + a0 + kc*512);
        f16x8 ah1 = ld8h(cenh + a1 + kc*512), al1 = ld8h(cenl + a1 + kc*512);
        h0 = __builtin_amdgcn_mfma_f32_16x16x32_f16(ah0, bh, h0, 0,0,0);
        c0 = __builtin_amdgcn_mfma_f32_16x16x32_f16(al0, bh, c0, 0,0,0);
        c0 = __builtin_amdgcn_mfma_f32_16x16x32_f16(ah0, bl, c0, 0,0,0);
        h1 = __builtin_amdgcn_mfma_f32_16x16x32_f16(ah1, bh, h1, 0,0,0);
        c1 = __builtin_amdgcn_mfma_f32_16x16x32_f16(al1, bh, c1, 0,0,0);
        c1 = __builtin_amdgcn_mfma_f32_16x16x32_f16(ah1, bl, c1, 0,0,0);
    }
    int rg = lane >> 4, fr = lane & 15;
    const float inv = 1.0f/4096.0f;
    #pragma unroll
    for (int rr = 0; rr < 4; ++rr) {
        red[wv][rg*4+rr][fr]      = h0[rr] + c0[rr]*inv;
        red[wv][16+rg*4+rr][fr]   = h1[rr] + c1[rr]*inv;
    }
    __syncthreads();
    int r = tid >> 4, c = tid & 15;   // 512 threads = 32x16
    float s = red[0][r][c]+red[1][r][c]+red[2][r][c]+red[3][r][c]
            + red[4][r][c]+red[5][r][c]+red[6][r][c]+red[7][r][c];
    int m = bm*32 + r, n = bn*16 + c;
    size_t d = fragoff(m, n, 32);
    f16* ctxh = (f16*)(ws + OFF_CTXH);
    f16* ctxl = (f16*)(ws + OFF_CTXL);
    fsplit(s, &ctxh[d], &ctxl[d]);
}

// ---------------- step kernel 2: fused gate GEMMs + GRU ----------------
// 264 blocks x 256 thr: block = (module i, 16 h-cols) x 128 rows; wave = 32 rows.
__global__ __launch_bounds__(256) void k_fused(char* ws,
    const float* __restrict__ bih0, const float* __restrict__ bih1,
    const float* __restrict__ bih2, const float* __restrict__ bih3,
    const float* __restrict__ bhh0, const float* __restrict__ bhh1,
    const float* __restrict__ bhh2, const float* __restrict__ bhh3,
    float* __restrict__ out, int t, int par)
{
    int tid = threadIdx.x, lane = tid & 63, wv = tid >> 6;
    int fr = lane & 15, rg = lane >> 4;
    int tile = blockIdx.x;
    int i, jt;
    if (tile < 64)       { i = 0; jt = tile; }
    else if (tile < 128) { i = 1; jt = tile - 64; }
    else if (tile < 192) { i = 2; jt = tile - 128; }
    else                 { i = 3; jt = tile - 192; }
    const int H  = (i == 3) ? 1152 : 1024;
    const int K1 = (i == 0) ? 384 : 256;
    const int Kc1 = K1 >> 5, KcH = H >> 5, Ht = H >> 4;

    const f16* WihH = (const f16*)(ws + (i==0?OFF_WIHH0 : i==1?OFF_WIHH1 : i==2?OFF_WIHH2 : OFF_WIHH3));
    const f16* WihL = (const f16*)(ws + (i==0?OFF_WIHL0 : i==1?OFF_WIHL1 : i==2?OFF_WIHL2 : OFF_WIHL3));
    const f16* WhhH = (const f16*)(ws + (i==0?OFF_WHHH0 : i==1?OFF_WHHH1 : i==2?OFF_WHHH2 : OFF_WHHH3));
    const f16* WhhL = (const f16*)(ws + (i==0?OFF_WHHL0 : i==1?OFF_WHHL1 : i==2?OFF_WHHL2 : OFF_WHHL3));

    size_t lb = (size_t)lane*8;
    size_t b1[3], b2[3];
    #pragma unroll
    for (int s = 0; s < 3; ++s) {
        b1[s] = ((size_t)(s*Ht + jt)*Kc1)*512 + lb;
        b2[s] = ((size_t)(s*Ht + jt)*KcH)*512 + lb;
    }
    int mt0 = wv*2;
    f32x4 aRh[2]={{},{}}, aRc[2]={{},{}}, aZh[2]={{},{}}, aZc[2]={{},{}};
    f32x4 aIh[2]={{},{}}, aIc[2]={{},{}}, aNh[2]={{},{}}, aNc[2]={{},{}};

    // ---- ih GEMM: A = (i==0 ? [x_t | ctx0] : ctx_i) ----
    {
        const f16* XH_ = (const f16*)(ws + OFF_XH);
        const f16* XL_ = (const f16*)(ws + OFF_XL);
        const f16* CH_ = (const f16*)(ws + OFF_CTXH);
        const f16* CL_ = (const f16*)(ws + OFF_CTXL);
        size_t xb0 = ((size_t)(t*8 + mt0)*4)*512 + lb, xb1 = xb0 + 4*512;
        size_t cb0 = ((size_t)mt0*32)*512 + lb,        cb1 = cb0 + 32*512;
        #pragma unroll 2
        for (int kc = 0; kc < Kc1; ++kc) {
            f16x8 ah0, al0, ah1, al1;
            if (i == 0 && kc < 4) {
                ah0 = ld8h(XH_ + xb0 + kc*512); al0 = ld8h(XL_ + xb0 + kc*512);
                ah1 = ld8h(XH_ + xb1 + kc*512); al1 = ld8h(XL_ + xb1 + kc*512);
            } else {
                int ck = (i == 0) ? kc - 4 : i*8 + kc;
                ah0 = ld8h(CH_ + cb0 + ck*512); al0 = ld8h(CL_ + cb0 + ck*512);
                ah1 = ld8h(CH_ + cb1 + ck*512); al1 = ld8h(CL_ + cb1 + ck*512);
            }
            f16x8 bh, bl;
            bh = ld8h(WihH + b1[0] + kc*512); bl = ld8h(WihL + b1[0] + kc*512);
            aRh[0] = __builtin_amdgcn_mfma_f32_16x16x32_f16(ah0, bh, aRh[0],0,0,0);
            aRc[0] = __builtin_amdgcn_mfma_f32_16x16x32_f16(al0, bh, aRc[0],0,0,0);
            aRc[0] = __builtin_amdgcn_mfma_f32_16x16x32_f16(ah0, bl, aRc[0],0,0,0);
            aRh[1] = __builtin_amdgcn_mfma_f32_16x16x32_f16(ah1, bh, aRh[1],0,0,0);
            aRc[1] = __builtin_amdgcn_mfma_f32_16x16x32_f16(al1, bh, aRc[1],0,0,0);
            aRc[1] = __builtin_amdgcn_mfma_f32_16x16x32_f16(ah1, bl, aRc[1],0,0,0);
            bh = ld8h(WihH + b1[1] + kc*512); bl = ld8h(WihL + b1[1] + kc*512);
            aZh[0] = __builtin_amdgcn_mfma_f32_16x16x32_f16(ah0, bh, aZh[0],0,0,0);
            aZc[0] = __builtin_amdgcn_mfma_f32_16x16x32_f16(al0, bh, aZc[0],0,0,0);
            aZc[0] = __builtin_amdgcn_mfma_f32_16x16x32_f16(ah0, bl, aZc[0],0,0,0);
            aZh[1] = __builtin_amdgcn_mfma_f32_16x16x32_f16(ah1, bh, aZh[1],0,0,0);
            aZc[1] = __builtin_amdgcn_mfma_f32_16x16x32_f16(al1, bh, aZc[1],0,0,0);
            aZc[1] = __builtin_amdgcn_mfma_f32_16x16x32_f16(ah1, bl, aZc[1],0,0,0);
            bh = ld8h(WihH + b1[2] + kc*512); bl = ld8h(WihL + b1[2] + kc*512);
            aIh[0] = __builtin_amdgcn_mfma_f32_16x16x32_f16(ah0, bh, aIh[0],0,0,0);
            aIc[0] = __builtin_amdgcn_mfma_f32_16x16x32_f16(al0, bh, aIc[0],0,0,0);
            aIc[0] = __builtin_amdgcn_mfma_f32_16x16x32_f16(ah0, bl, aIc[0],0,0,0);
            aIh[1] = __builtin_amdgcn_mfma_f32_16x16x32_f16(ah1, bh, aIh[1],0,0,0);
            aIc[1] = __builtin_amdgcn_mfma_f32_16x16x32_f16(al1, bh, aIc[1],0,0,0);
            aIc[1] = __builtin_amdgcn_mfma_f32_16x16x32_f16(ah1, bl, aIc[1],0,0,0);
        }
    }
    // ---- hh GEMM: A = h_prev (parity par) ----
    {
        const f16* HHp = hh_ptr(ws, par, i);
        const f16* HLp = hl_ptr(ws, par, i);
        size_t hb0 = ((size_t)mt0*KcH)*512 + lb, hb1 = hb0 + (size_t)KcH*512;
        #pragma unroll 2
        for (int kc = 0; kc < KcH; ++kc) {
            f16x8 ah0 = ld8h(HHp + hb0 + kc*512), al0 = ld8h(HLp + hb0 + kc*512);
            f16x8 ah1 = ld8h(HHp + hb1 + kc*512), al1 = ld8h(HLp + hb1 + kc*512);
            f16x8 bh, bl;
            bh = ld8h(WhhH + b2[0] + kc*512); bl = ld8h(WhhL + b2[0] + kc*512);
            aRh[0] = __builtin_amdgcn_mfma_f32_16x16x32_f16(ah0, bh, aRh[0],0,0,0);
            aRc[0] = __builtin_amdgcn_mfma_f32_16x16x32_f16(al0, bh, aRc[0],0,0,0);
            aRc[0] = __builtin_amdgcn_mfma_f32_16x16x32_f16(ah0, bl, aRc[0],0,0,0);
            aRh[1] = __builtin_amdgcn_mfma_f32_16x16x32_f16(ah1, bh, aRh[1],0,0,0);
            aRc[1] = __builtin_amdgcn_mfma_f32_16x16x32_f16(al1, bh, aRc[1],0,0,0);
            aRc[1] = __builtin_amdgcn_mfma_f32_16x16x32_f16(ah1, bl, aRc[1],0,0,0);
            bh = ld8h(WhhH + b2[1] + kc*512); bl = ld8h(WhhL + b2[1] + kc*512);
            aZh[0] = __builtin_amdgcn_mfma_f32_16x16x32_f16(ah0, bh, aZh[0],0,0,0);
            aZc[0] = __builtin_amdgcn_mfma_f32_16x16x32_f16(al0, bh, aZc[0],0,0,0);
            aZc[0] = __builtin_amdgcn_mfma_f32_16x16x32_f16(ah0, bl, aZc[0],0,0,0);
            aZh[1] = __builtin_amdgcn_mfma_f32_16x16x32_f16(ah1, bh, aZh[1],0,0,0);
            aZc[1] = __builtin_amdgcn_mfma_f32_16x16x32_f16(al1, bh, aZc[1],0,0,0);
            aZc[1] = __builtin_amdgcn_mfma_f32_16x16x32_f16(ah1, bl, aZc[1],0,0,0);
            bh = ld8h(WhhH + b2[2] + kc*512); bl = ld8h(WhhL + b2[2] + kc*512);
            aNh[0] = __builtin_amdgcn_mfma_f32_16x16x32_f16(ah0, bh, aNh[0],0,0,0);
            aNc[0] = __builtin_amdgcn_mfma_f32_16x16x32_f16(al0, bh, aNc[0],0,0,0);
            aNc[0] = __builtin_amdgcn_mfma_f32_16x16x32_f16(ah0, bl, aNc[0],0,0,0);
            aNh[1] = __builtin_amdgcn_mfma_f32_16x16x32_f16(ah1, bh, aNh[1],0,0,0);
            aNc[1] = __builtin_amdgcn_mfma_f32_16x16x32_f16(al1, bh, aNc[1],0,0,0);
            aNc[1] = __builtin_amdgcn_mfma_f32_16x16x32_f16(ah1, bl, aNc[1],0,0,0);
        }
    }

    // ---- GRU epilogue ----
    const float* bihp = (i==0?bih0 : i==1?bih1 : i==2?bih2 : bih3);
    const float* bhhp = (i==0?bhh0 : i==1?bhh1 : i==2?bhh2 : bhh3);
    int j = jt*16 + fr;
    float bir = bihp[j], biz = bihp[H+j], bin = bihp[2*H+j];
    float bhr = bhhp[j], bhz = bhhp[H+j], bhn = bhhp[2*H+j];
    const float* hfP = hf_ptr(ws, par, i);
    float* hfN = hf_ptr(ws, par^1, i);
    f16 *hhN = hh_ptr(ws, par^1, i), *hlN = hl_ptr(ws, par^1, i);
    f16* cenhN = (f16*)(ws + OFF_CENH) + (size_t)(par^1)*NCEN;
    f16* cenlN = (f16*)(ws + OFF_CENL) + (size_t)(par^1)*NCEN;
    const float inv = 1.0f/4096.0f;
    #pragma unroll
    for (int mf = 0; mf < 2; ++mf) {
        #pragma unroll
        for (int rr = 0; rr < 4; ++rr) {
            float r_ = aRh[mf][rr] + aRc[mf][rr]*inv + bir + bhr;
            float z_ = aZh[mf][rr] + aZc[mf][rr]*inv + biz + bhz;
            float in_ = aIh[mf][rr] + aIc[mf][rr]*inv + bin;
            float hn_ = aNh[mf][rr] + aNc[mf][rr]*inv + bhn;
            float rgt = 1.f/(1.f + expf(-r_));
            float zgt = 1.f/(1.f + expf(-z_));
            float ngt = tanhf(in_ + rgt*hn_);
            int m = wv*32 + mf*16 + rg*4 + rr;
            float hp = hfP[(size_t)m*H + j];
            float hnew = (1.f - zgt)*ngt + zgt*hp;
            hfN[(size_t)m*H + j] = hnew;
            size_t hd = fragoff(m, j, KcH);
            fsplit(hnew, &hhN[hd], &hlN[hd]);
            if (i < 3) {
                size_t cd = fragoff(m, i*1024 + j, 128);
                fsplit(hnew, &cenhN[cd], &cenlN[cd]);
            } else if (j >= 128) {
                size_t cd = fragoff(m, 3072 + j - 128, 128);
                fsplit(hnew, &cenhN[cd], &cenlN[cd]);
            } else {
                out[((size_t)m*256 + t)*128 + j] = hnew;
            }
        }
    }
}

// ---------------- host ----------------
extern "C" void kernel_launch(void* const* d_in, const int* in_sizes, int n_in,
                              void* d_out, int out_size, void* d_ws, size_t ws_size,
                              hipStream_t stream)
{
    char* ws = (char*)d_ws;
    const float* inp   = (const float*)d_in[0];
    const float* cini  = (const float*)d_in[1];
    const float* mini  = (const float*)d_in[2];
    const float* mlast = (const float*)d_in[3];
    const float *pm[4], *wih[4], *whh[4], *bih[4], *bhh[4];
    for (int i = 0; i < 4; ++i) {
        pm[i]  = (const float*)d_in[4 + 5*i];
        wih[i] = (const float*)d_in[5 + 5*i];
        whh[i] = (const float*)d_in[6 + 5*i];
        bih[i] = (const float*)d_in[7 + 5*i];
        bhh[i] = (const float*)d_in[8 + 5*i];
    }
    float* out = (float*)d_out;

    k_repack_x<<<2048, 256, 0, stream>>>(inp, (f16*)(ws+OFF_XH), (f16*)(ws+OFF_XL));
    k_repack_pm<<<512, 256, 0, stream>>>(pm[0], pm[1], pm[2], pm[3],
                                         (f16*)(ws+OFF_PMH), (f16*)(ws+OFF_PML));
    k_repack_w<<<3072, 256, 0, stream>>>(wih[0], (f16*)(ws+OFF_WIHH0), (f16*)(ws+OFF_WIHL0), 384);
    k_repack_w<<<3072, 256, 0, stream>>>(wih[1], (f16*)(ws+OFF_WIHH1), (f16*)(ws+OFF_WIHL1), 256);
    k_repack_w<<<3072, 256, 0, stream>>>(wih[2], (f16*)(ws+OFF_WIHH2), (f16*)(ws+OFF_WIHL2), 256);
    k_repack_w<<<3456, 256, 0, stream>>>(wih[3], (f16*)(ws+OFF_WIHH3), (f16*)(ws+OFF_WIHL3), 256);
    k_repack_w<<<3072, 256, 0, stream>>>(whh[0], (f16*)(ws+OFF_WHHH0), (f16*)(ws+OFF_WHHL0), 1024);
    k_repack_w<<<3072, 256, 0, stream>>>(whh[1], (f16*)(ws+OFF_WHHH1), (f16*)(ws+OFF_WHHL1), 1024);
    k_repack_w<<<3072, 256, 0, stream>>>(whh[2], (f16*)(ws+OFF_WHHH2), (f16*)(ws+OFF_WHHL2), 1024);
    k_repack_w<<<3456, 256, 0, stream>>>(whh[3], (f16*)(ws+OFF_WHHH3), (f16*)(ws+OFF_WHHL3), 1152);
    k_init_cen<<<256, 256, 0, stream>>>(cini, ws);
    k_init_mod<<<192, 256, 0, stream>>>(mini, ws);
    k_init_last<<<128, 256, 0, stream>>>(mlast, ws);

    for (int t = 0; t < 256; ++t) {
        int par = t & 1;
        k_ctx<<<256, 512, 0, stream>>>(ws, par);
        k_fused<<<264, 256, 0, stream>>>(ws,
            bih[0], bih[1], bih[2], bih[3],
            bhh[0], bhh[1], bhh[2], bhh[3],
            out, t, par);
    }
    (void)in_sizes; (void)n_in; (void)out_size; (void)ws_size; (void)WS_NEED;
}